// Round 6
// baseline (1671.765 us; speedup 1.0000x reference)
//
#include <hip/hip_runtime.h>

typedef _Float16 f16;
typedef _Float16 half2t __attribute__((ext_vector_type(2)));
typedef _Float16 half8 __attribute__((ext_vector_type(8)));
typedef float floatx4 __attribute__((ext_vector_type(4)));

#define B_ 128
#define S_ 1024
#define D_ 256
#define H_ 256
#define N3H 768

// ---------------------------------------------------------------------------
// Pack W_hh fp32 [256][768] -> uint-packed half2 along K: whh2[k2*768 + j]
// holds (W[2k2][j], W[2k2+1][j]) as two fp16 in one dword.
// ---------------------------------------------------------------------------
__global__ void pack_whh_kernel(const float* __restrict__ whh,
                                unsigned int* __restrict__ whh2) {
  int idx = blockIdx.x * 256 + threadIdx.x;
  if (idx >= 128 * N3H) return;
  int k2 = idx / N3H;
  int j  = idx - k2 * N3H;
  f16 lo = (f16)whh[(2 * k2) * N3H + j];
  f16 hi = (f16)whh[(2 * k2 + 1) * N3H + j];
  unsigned int v = ((unsigned int)__builtin_bit_cast(unsigned short, lo)) |
                   ((unsigned int)__builtin_bit_cast(unsigned short, hi) << 16);
  whh2[idx] = v;
}

// ---------------------------------------------------------------------------
// Phase 1: gx[M=131072][768] = X[M][256] @ W_ih[256][768] + b_ih  (fp16 out)
// 128x128 block tile, 4 waves each computing 64x64 via 4x4 MFMA 16x16x32 f16.
// ---------------------------------------------------------------------------
__global__ __launch_bounds__(256) void gemm_gx_kernel(
    const float* __restrict__ X, const float* __restrict__ W,
    const float* __restrict__ bias, f16* __restrict__ gx) {
  __shared__ __align__(16) f16 As[128][40];  // [m][k], pad 32->40
  __shared__ __align__(16) f16 Bs[128][40];  // [n][k] (transposed on store)
  const int m0 = blockIdx.x * 128;
  const int n0 = blockIdx.y * 128;
  const int tid = threadIdx.x;
  const int lane = tid & 63, wave = tid >> 6;
  const int wr = (wave >> 1) * 64, wc = (wave & 1) * 64;
  const int quad = lane >> 4, l16 = lane & 15;

  floatx4 acc[4][4];
#pragma unroll
  for (int i = 0; i < 4; i++)
#pragma unroll
    for (int j = 0; j < 4; j++) acc[i][j] = (floatx4)0.f;

  const int arow = tid >> 1, akh = (tid & 1) * 16;
  const int bkr = tid >> 3, bns = (tid & 7) * 16;

  for (int k0 = 0; k0 < 256; k0 += 32) {
    __syncthreads();
    {  // stage A: rows m0..m0+128, k0..k0+32
      const float* src = X + (size_t)(m0 + arow) * 256 + k0 + akh;
      float4 f0 = ((const float4*)src)[0];
      float4 f1 = ((const float4*)src)[1];
      float4 f2 = ((const float4*)src)[2];
      float4 f3 = ((const float4*)src)[3];
      half8 v0 = {(f16)f0.x, (f16)f0.y, (f16)f0.z, (f16)f0.w,
                  (f16)f1.x, (f16)f1.y, (f16)f1.z, (f16)f1.w};
      half8 v1 = {(f16)f2.x, (f16)f2.y, (f16)f2.z, (f16)f2.w,
                  (f16)f3.x, (f16)f3.y, (f16)f3.z, (f16)f3.w};
      *(half8*)&As[arow][akh] = v0;
      *(half8*)&As[arow][akh + 8] = v1;
    }
    {  // stage B transposed: W rows k0..k0+32, cols n0..n0+128 -> Bs[n][k]
      const float* src = W + (size_t)(k0 + bkr) * N3H + n0 + bns;
      float4 f0 = ((const float4*)src)[0];
      float4 f1 = ((const float4*)src)[1];
      float4 f2 = ((const float4*)src)[2];
      float4 f3 = ((const float4*)src)[3];
      float fv[16] = {f0.x, f0.y, f0.z, f0.w, f1.x, f1.y, f1.z, f1.w,
                      f2.x, f2.y, f2.z, f2.w, f3.x, f3.y, f3.z, f3.w};
#pragma unroll
      for (int i = 0; i < 16; ++i) Bs[bns + i][bkr] = (f16)fv[i];
    }
    __syncthreads();
    half8 a[4], b[4];
#pragma unroll
    for (int i = 0; i < 4; ++i) a[i] = *(const half8*)&As[wr + i * 16 + l16][quad * 8];
#pragma unroll
    for (int j = 0; j < 4; ++j) b[j] = *(const half8*)&Bs[wc + j * 16 + l16][quad * 8];
#pragma unroll
    for (int i = 0; i < 4; ++i)
#pragma unroll
      for (int j = 0; j < 4; ++j)
        acc[i][j] = __builtin_amdgcn_mfma_f32_16x16x32_f16(a[i], b[j], acc[i][j], 0, 0, 0);
  }
#pragma unroll
  for (int i = 0; i < 4; ++i) {
#pragma unroll
    for (int j = 0; j < 4; ++j) {
      int col = n0 + wc + j * 16 + l16;
      float bv = bias[col];
#pragma unroll
      for (int r = 0; r < 4; ++r) {
        int row = m0 + wr + i * 16 + quad * 4 + r;
        gx[(size_t)row * N3H + col] = (f16)(acc[i][j][r] + bv);
      }
    }
  }
}

// ---------------------------------------------------------------------------
// Phase 2: sequential GRU recurrence. One block per batch element. 768
// threads; thread j owns gh column j. h lives in LDS (fp16), broadcast-read.
//
// R6 = R5 with the name collision fixed (param renamed w2 -> wtab, named
// registers prefixed wr_). Theory unchanged: VGPR_Count froze at 84 through
// launch_bounds / waves_per_eu(3,3) / asm pinning because the 512 B
// `w[128]` alloca was demoted to SCRATCH before RA, so every timestep
// re-streamed 384 KB/CU from L2 (50 GB/dispatch = 36 TB/s = L2 ceiling;
// matches 3200 cyc/step, VALUBusy 31%). Named scalars are SSA values - no
// alloca to demote. asm pins prevent sinking/remat into the t-loop;
// waves_per_eu(3,3) gives RA a 168-VGPR budget (128 weights + ~30 working).
// Verification gate: VGPR_Count >= 150.
// ---------------------------------------------------------------------------
#define FORALL_W(M) \
  M(0) M(1) M(2) M(3) M(4) M(5) M(6) M(7) \
  M(8) M(9) M(10) M(11) M(12) M(13) M(14) M(15) \
  M(16) M(17) M(18) M(19) M(20) M(21) M(22) M(23) \
  M(24) M(25) M(26) M(27) M(28) M(29) M(30) M(31) \
  M(32) M(33) M(34) M(35) M(36) M(37) M(38) M(39) \
  M(40) M(41) M(42) M(43) M(44) M(45) M(46) M(47) \
  M(48) M(49) M(50) M(51) M(52) M(53) M(54) M(55) \
  M(56) M(57) M(58) M(59) M(60) M(61) M(62) M(63) \
  M(64) M(65) M(66) M(67) M(68) M(69) M(70) M(71) \
  M(72) M(73) M(74) M(75) M(76) M(77) M(78) M(79) \
  M(80) M(81) M(82) M(83) M(84) M(85) M(86) M(87) \
  M(88) M(89) M(90) M(91) M(92) M(93) M(94) M(95) \
  M(96) M(97) M(98) M(99) M(100) M(101) M(102) M(103) \
  M(104) M(105) M(106) M(107) M(108) M(109) M(110) M(111) \
  M(112) M(113) M(114) M(115) M(116) M(117) M(118) M(119) \
  M(120) M(121) M(122) M(123) M(124) M(125) M(126) M(127)

#define LDW(i) unsigned int wr_##i = wtabp[(i) * N3H];
#define PINW(i) asm volatile("" : "+v"(wr_##i));

#define FD(hc_comp, wi, acc_)                                              \
  acc_ = __builtin_amdgcn_fdot2(__builtin_bit_cast(half2t, hc_comp),       \
                                __builtin_bit_cast(half2t, wi), acc_, false);

#define DOT4(c, i0, i1, i2, i3)      \
  {                                  \
    uint4 hc = h4[c];                \
    FD(hc.x, wr_##i0, a0)            \
    FD(hc.y, wr_##i1, a1)            \
    FD(hc.z, wr_##i2, a2)            \
    FD(hc.w, wr_##i3, a3)            \
  }

__global__ __launch_bounds__(768)
__attribute__((amdgpu_waves_per_eu(3, 3))) void gru_rec_kernel(
    const f16* __restrict__ gx,             // [128*1024][768]
    const unsigned int* __restrict__ wtab,  // [128][768] packed half2
    const float* __restrict__ bhh,          // [768]
    const float* __restrict__ mask,         // [128][1024]
    float* __restrict__ out) {              // [128][1024][256]
  const int b = blockIdx.x;
  const int j = threadIdx.x;
  __shared__ __align__(16) f16 h16[256];
  __shared__ float rz[512];

  const unsigned int* wtabp = wtab + j;
  FORALL_W(LDW)
  FORALL_W(PINW)

  if (j < 256) h16[j] = (f16)0.f;
  const float bj = bhh[j];
  const f16* gxp = gx + (size_t)b * S_ * N3H + j;
  const float* mp = mask + (size_t)b * S_;
  float* outp = out + (size_t)b * S_ * H_;

  float hreg = 0.f;  // fp32 copy of h[j-512] for owner threads (j >= 512)

  __syncthreads();

  f16 cur_gx = gxp[0];
  float cur_m = mp[0];
#pragma unroll 1
  for (int t = 0; t < S_; ++t) {
    f16 nxt_gx = (f16)0.f;
    float nxt_m = 0.f;
    if (t + 1 < S_) {
      nxt_gx = gxp[(size_t)(t + 1) * N3H];
      nxt_m = mp[t + 1];
    }
    // --- gh_j = <h, W_hh[:,j]>: 4 independent fdot2 chains for ILP ---
    float a0 = 0.f, a1 = 0.f, a2 = 0.f, a3 = 0.f;
    const uint4* h4 = (const uint4*)h16;
    DOT4(0, 0, 1, 2, 3)
    DOT4(1, 4, 5, 6, 7)
    DOT4(2, 8, 9, 10, 11)
    DOT4(3, 12, 13, 14, 15)
    DOT4(4, 16, 17, 18, 19)
    DOT4(5, 20, 21, 22, 23)
    DOT4(6, 24, 25, 26, 27)
    DOT4(7, 28, 29, 30, 31)
    DOT4(8, 32, 33, 34, 35)
    DOT4(9, 36, 37, 38, 39)
    DOT4(10, 40, 41, 42, 43)
    DOT4(11, 44, 45, 46, 47)
    DOT4(12, 48, 49, 50, 51)
    DOT4(13, 52, 53, 54, 55)
    DOT4(14, 56, 57, 58, 59)
    DOT4(15, 60, 61, 62, 63)
    DOT4(16, 64, 65, 66, 67)
    DOT4(17, 68, 69, 70, 71)
    DOT4(18, 72, 73, 74, 75)
    DOT4(19, 76, 77, 78, 79)
    DOT4(20, 80, 81, 82, 83)
    DOT4(21, 84, 85, 86, 87)
    DOT4(22, 88, 89, 90, 91)
    DOT4(23, 92, 93, 94, 95)
    DOT4(24, 96, 97, 98, 99)
    DOT4(25, 100, 101, 102, 103)
    DOT4(26, 104, 105, 106, 107)
    DOT4(27, 108, 109, 110, 111)
    DOT4(28, 112, 113, 114, 115)
    DOT4(29, 116, 117, 118, 119)
    DOT4(30, 120, 121, 122, 123)
    DOT4(31, 124, 125, 126, 127)
    float gh = ((a0 + a1) + (a2 + a3)) + bj;
    float gxv = (float)cur_gx;
    if (j < 512) {  // r (0..255) and z (256..511) gates — wave-uniform branch
      float xa = gxv + gh;
      xa = fminf(fmaxf(xa, -30.f), 30.f);
      rz[j] = 1.f / (1.f + __expf(-xa));
    }
    __syncthreads();
    if (j >= 512) {  // n gate + state update — wave-uniform branch
      const int jj = j - 512;
      float r = rz[jj], z = rz[jj + 256];
      float xn = gxv + r * gh;
      xn = fminf(fmaxf(xn, -15.f), 15.f);
      float e = __expf(2.f * xn);
      float n = (e - 1.f) / (e + 1.f);  // tanh
      float hp = hreg;
      float hn = (1.f - z) * n + z * hp;
      float hv = cur_m * hn + (1.f - cur_m) * hp;
      hreg = hv;
      h16[jj] = (f16)hv;
      outp[(size_t)t * H_ + jj] = hv;
    }
    __syncthreads();
    cur_gx = nxt_gx;
    cur_m = nxt_m;
  }
}

// ---------------------------------------------------------------------------
extern "C" void kernel_launch(void* const* d_in, const int* in_sizes, int n_in,
                              void* d_out, int out_size, void* d_ws, size_t ws_size,
                              hipStream_t stream) {
  const float* x    = (const float*)d_in[0];
  const float* mask = (const float*)d_in[1];
  const float* Wih  = (const float*)d_in[2];
  const float* Whh  = (const float*)d_in[3];
  const float* bih  = (const float*)d_in[4];
  const float* bhh  = (const float*)d_in[5];
  float* out = (float*)d_out;

  // ws layout: gx16 (201.3 MB) | whh2 packed (384 KB)
  f16* gx = (f16*)d_ws;
  unsigned int* whh2 =
      (unsigned int*)((char*)d_ws + (size_t)B_ * S_ * N3H * sizeof(f16));

  pack_whh_kernel<<<dim3((128 * N3H + 255) / 256), dim3(256), 0, stream>>>(Whh, whh2);
  gemm_gx_kernel<<<dim3((B_ * S_) / 128, N3H / 128), dim3(256), 0, stream>>>(x, Wih, bih, gx);
  gru_rec_kernel<<<dim3(B_), dim3(768), 0, stream>>>(gx, whh2, bhh, mask, out);
}